// Round 10
// baseline (123.425 us; speedup 1.0000x reference)
//
#include <hip/hip_runtime.h>
#include <stdint.h>

#define Bsz 16384
#define Hh  512
#define Kd  1024      // I + H
#define BM  256       // M rows per workgroup
#define BNJ 32        // j columns per workgroup (x5 gates)
#define BK  64        // K per tile
#define NT  16        // K tiles

// LDS buffer: A 32KB + B 20KB = 52KB; three buffers = 156KB (1 wg/CU)
#define BUFB 53248

typedef __attribute__((ext_vector_type(8))) short bf16x8;
typedef __attribute__((ext_vector_type(4))) float f32x4;
typedef __attribute__((ext_vector_type(8))) unsigned short u16x8;

__device__ __forceinline__ unsigned short f2bf(float f) {
    union { float f; unsigned u; } v; v.f = f;
    unsigned u = v.u;
    return (unsigned short)((u + 0x7fffu + ((u >> 16) & 1u)) >> 16);
}
__device__ __forceinline__ float fast_tanh(float x) {
    float e = __expf(2.f * x);
    return (e - 1.f) / (e + 1.f);
}
__device__ __forceinline__ float fast_sigmoid(float x) {
    return 1.f / (1.f + __expf(-x));
}

// ---------------- pack A = [x | h_prev] -> bf16 [16384][1024] ----------------
__global__ void pack_A(const float* __restrict__ x, const float* __restrict__ h,
                       unsigned short* __restrict__ A) {
    const long total = (long)Bsz * Kd / 8;
    for (long i = (long)blockIdx.x * blockDim.x + threadIdx.x; i < total;
         i += (long)gridDim.x * blockDim.x) {
        long row = i >> 7;
        int  col = ((int)(i & 127)) << 3;
        const float* src = (col < 512) ? (x + row * 512 + col)
                                       : (h + row * 512 + (col - 512));
        float4 f0 = *(const float4*)(src);
        float4 f1 = *(const float4*)(src + 4);
        u16x8 o;
        o[0]=f2bf(f0.x); o[1]=f2bf(f0.y); o[2]=f2bf(f0.z); o[3]=f2bf(f0.w);
        o[4]=f2bf(f1.x); o[5]=f2bf(f1.y); o[6]=f2bf(f1.z); o[7]=f2bf(f1.w);
        *(u16x8*)(A + (i << 3)) = o;
    }
}

// ---- pack B into fragment-linear layout ----
// elem addr = jgrp*81920 + g*16384 + kt*1024 + kh*512 + l*8 + e
//  = W[g][ j = jgrp*16 + (l&15) ][ k = kt*64 + kh*32 + (l>>4)*8 + e ]
__global__ void pack_B(const float* __restrict__ Wxi, const float* __restrict__ Whi,
                       const float* __restrict__ Wxf, const float* __restrict__ Whf,
                       const float* __restrict__ Wxc, const float* __restrict__ Whc,
                       const float* __restrict__ Wxo, const float* __restrict__ Who,
                       const float* __restrict__ We,
                       const float* __restrict__ bxi, const float* __restrict__ bhi,
                       const float* __restrict__ bxf, const float* __restrict__ bhf,
                       const float* __restrict__ bxc, const float* __restrict__ bhc,
                       const float* __restrict__ bxo, const float* __restrict__ bho,
                       const float* __restrict__ be,
                       unsigned short* __restrict__ Bp, float* __restrict__ bias) {
    const long id = (long)blockIdx.x * blockDim.x + threadIdx.x;  // 327680 total
    if (id < 327680) {
        int blk = (int)(id >> 6);
        int l   = (int)(id & 63);
        int kh  = blk & 1;
        int kt  = (blk >> 1) & 15;
        int rest = blk >> 5;
        int g    = rest % 5;
        int jgrp = rest / 5;
        int j  = jgrp * 16 + (l & 15);
        int k0 = kt * 64 + kh * 32 + ((l >> 4) << 3);
        const float* src;
        if (g == 4) {
            src = We + (long)j * 1024 + k0;
        } else {
            const float* Wx = (g == 0) ? Wxi : (g == 1) ? Wxf : (g == 2) ? Wxc : Wxo;
            const float* Wh = (g == 0) ? Whi : (g == 1) ? Whf : (g == 2) ? Whc : Who;
            src = (k0 < 512) ? (Wx + (long)j * 512 + k0)
                             : (Wh + (long)j * 512 + (k0 - 512));
        }
        float4 f0 = *(const float4*)(src);
        float4 f1 = *(const float4*)(src + 4);
        u16x8 o;
        o[0]=f2bf(f0.x); o[1]=f2bf(f0.y); o[2]=f2bf(f0.z); o[3]=f2bf(f0.w);
        o[4]=f2bf(f1.x); o[5]=f2bf(f1.y); o[6]=f2bf(f1.z); o[7]=f2bf(f1.w);
        *(u16x8*)(Bp + (long)blk * 512 + l * 8) = o;
    }
    if (id < 2560) {
        int row = (int)id;
        int g = row >> 9, j = row & 511;
        float b;
        if (g == 4) b = be[j];
        else {
            const float* bx = (g == 0) ? bxi : (g == 1) ? bxf : (g == 2) ? bxc : bxo;
            const float* bh = (g == 0) ? bhi : (g == 1) ? bhf : (g == 2) ? bhc : bho;
            b = bx[j] + bh[j];
        }
        bias[row] = b;
    }
}

// ------- fused GEMM: m201-style phased schedule, 3-buffer depth-2, counted vmcnt -------
#define GL16(g, l) __builtin_amdgcn_global_load_lds( \
    (const __attribute__((address_space(1))) unsigned int*)(g), \
    (__attribute__((address_space(3))) unsigned int*)(l), 16, 0, 0)

#define VM_I(n)    asm volatile("s_waitcnt vmcnt(" #n ")" ::: "memory")
#define VM(n)      VM_I(n)
#define LGKM0()    asm volatile("s_waitcnt lgkmcnt(0)" ::: "memory")
#define BARRIER()  asm volatile("s_barrier" ::: "memory")
#define SCHED0()   __builtin_amdgcn_sched_barrier(0)

#define MF(a, b, c) __builtin_amdgcn_mfma_f32_16x16x32_bf16(a, b, c, 0, 0, 0)

// ds reads for one phase (kh fixed): 4 A frags + 5 B frags
#define RDPH(RBO, APK) do { \
    af[0] = *(const bf16x8*)(APK + (RBO) + 0 * 2048); \
    af[1] = *(const bf16x8*)(APK + (RBO) + 1 * 2048); \
    af[2] = *(const bf16x8*)(APK + (RBO) + 2 * 2048); \
    af[3] = *(const bf16x8*)(APK + (RBO) + 3 * 2048); \
} while (0)
#define RDB5(RBO, KH) do { \
    bq[0] = *(const bf16x8*)(bP + (RBO) + (0 + (KH)) * 1024); \
    bq[1] = *(const bf16x8*)(bP + (RBO) + (2 + (KH)) * 1024); \
    bq[2] = *(const bf16x8*)(bP + (RBO) + (4 + (KH)) * 1024); \
    bq[3] = *(const bf16x8*)(bP + (RBO) + (6 + (KH)) * 1024); \
    bq[4] = *(const bf16x8*)(bP + (RBO) + (8 + (KH)) * 1024); \
} while (0)

#define MFMA20() do { \
    __builtin_amdgcn_s_setprio(1); \
    _Pragma("unroll") \
    for (int g_ = 0; g_ < 5; ++g_) { \
        acc[g_][0] = MF(af[0], bq[g_], acc[g_][0]); \
        acc[g_][1] = MF(af[1], bq[g_], acc[g_][1]); \
        acc[g_][2] = MF(af[2], bq[g_], acc[g_][2]); \
        acc[g_][3] = MF(af[3], bq[g_], acc[g_][3]); \
    } \
    __builtin_amdgcn_s_setprio(0); \
} while (0)

// staging: A slot i (i<4): chunk c = tid + i*512; B slot i (i<3): unit u = wid + 8i (mod 20 dup)
#define GLA(SBO, T, I) GL16(asg + (I) * 65536 + (T) * 64, \
                            lds_raw + (SBO) + adst + (I) * 8192)
#define GLB(SBO, T, I) GL16(bsg##I + (T) * 1024, lds_raw + (SBO) + bdo##I)

// one K-tile = 2 phases (kh0, kh1); stage tile T+2 into SBO; vmcnt(WN) at ph1 end
#define TILE(RBO, SBO, T, STG, VMF, WN) do { \
    /* ---- phase 0 (kh0) ---- */ \
    RDPH(RBO, aPk0); RDB5(RBO, 0); \
    if (STG) { GLA(SBO, (T)+2, 0); GLA(SBO, (T)+2, 1); GLB(SBO, (T)+2, 0); } \
    BARRIER(); \
    LGKM0(); SCHED0(); \
    MFMA20(); \
    BARRIER(); \
    /* ---- phase 1 (kh1) ---- */ \
    RDPH(RBO, aPk1); RDB5(RBO, 1); \
    if (STG) { GLA(SBO, (T)+2, 2); GLA(SBO, (T)+2, 3); GLB(SBO, (T)+2, 1); GLB(SBO, (T)+2, 2); } \
    BARRIER(); \
    LGKM0(); SCHED0(); \
    MFMA20(); \
    if (VMF) VM(WN); \
    BARRIER(); \
} while (0)

__global__ __launch_bounds__(512, 2)
void xlstm_gemm(const unsigned short* __restrict__ A,
                const unsigned short* __restrict__ Bp,
                const float* __restrict__ bias,
                const float* __restrict__ c_prev,
                float* __restrict__ out) {
    __shared__ __align__(16) unsigned char lds_raw[3 * BUFB];  // 156 KB

    const int tid  = threadIdx.x;
    const int wid  = tid >> 6;
    const int lane = tid & 63;
    const int wm   = wid >> 1;    // 0..3 : M quarter (64 rows)
    const int wj   = wid & 1;     // 0..1 : j half (16 cols)
    const int fr   = lane & 15;
    const int q    = lane >> 4;

    // T1: bijective XCD swizzle (nwg = 1024, 1024 % 8 == 0)
    const int orig = blockIdx.x;
    const int wg   = (orig & 7) * 128 + (orig >> 3);
    const int mblk = wg >> 4;     // 0..63
    const int jblk = wg & 15;     // 0..15
    const long brow = (long)mblk * BM;
    const int  bcol = jblk * BNJ;

    f32x4 acc[5][4];
#pragma unroll
    for (int g = 0; g < 5; ++g)
#pragma unroll
        for (int m = 0; m < 4; ++m)
#pragma unroll
            for (int r = 0; r < 4; ++r) acc[g][m][r] = 0.f;

    bf16x8 af[4];
    bf16x8 bq[5];

    // ---- read-side LDS pointers (proven round-2..4 layout) ----
    const int aboff = (wm * 64 + fr) * 128;
    const int swz0  = ((q) ^ (fr & 7)) << 4;
    const int swz1  = ((4 | q) ^ (fr & 7)) << 4;
    const unsigned char* aPk0 = lds_raw + aboff + swz0;
    const unsigned char* aPk1 = lds_raw + aboff + swz1;
    const unsigned char* bP   = lds_raw + 32768 + wj * 10240 + lane * 16;

    // ---- staging pointers ----
    // A: chunk c = tid + i*512; row = c>>3 = (tid>>3) + i*64; src col swizzled by row&7
    const int r0_ = tid >> 3;
    const unsigned short* asg = A + (brow + r0_) * 1024L
                                  + (((tid & 7) ^ (r0_ & 7)) << 3);
    const int adst = tid * 16;
    // B: unit u = wid + 8*i; u>=20 wraps to u-20 (benign same-value dup)
    const unsigned short *bsg0, *bsg1, *bsg2;
    int bdo0, bdo1, bdo2;
#define BSTG_INIT(i) do { \
    int u_ = wid + 8 * (i); if (u_ >= 20) u_ -= 20; \
    int jl_ = u_ / 10; int rr_ = u_ - 10 * jl_; \
    int g_ = rr_ >> 1; int kh_ = rr_ & 1; \
    bsg##i = Bp + (long)(jblk * 2 + jl_) * 81920 + g_ * 16384 + kh_ * 512 + lane * 8; \
    bdo##i = 32768 + u_ * 1024 + lane * 16; \
} while (0)
    BSTG_INIT(0); BSTG_INIT(1); BSTG_INIT(2);
#undef BSTG_INIT

    // ---- prologue: stage tile 0 -> buf0, tile 1 -> buf1; certify tile 0 ----
    GLA(0, 0, 0); GLA(0, 0, 1); GLA(0, 0, 2); GLA(0, 0, 3);
    GLB(0, 0, 0); GLB(0, 0, 1); GLB(0, 0, 2);
    GLA(BUFB, 1, 0); GLA(BUFB, 1, 1); GLA(BUFB, 1, 2); GLA(BUFB, 1, 3);
    GLB(BUFB, 1, 0); GLB(BUFB, 1, 1); GLB(BUFB, 1, 2);
    VM(7);          // tile 0's 7 complete; tile 1's 7 in flight
    BARRIER();

    // ---- main loop: tile t reads buf t%3, stages t+2 into buf (t+2)%3 ----
    // steady vmcnt(7): certifies t+1 (issued in t-1), leaves t+2's 7 in flight
    for (int t = 0; t < 12; t += 3) {
        TILE(0 * BUFB, 2 * BUFB, t + 0, 1, 1, 7);
        TILE(1 * BUFB, 0 * BUFB, t + 1, 1, 1, 7);
        TILE(2 * BUFB, 1 * BUFB, t + 2, 1, 1, 7);
    }
    TILE(0 * BUFB, 2 * BUFB, 12, 1, 1, 7);
    TILE(1 * BUFB, 0 * BUFB, 13, 1, 1, 7);   // stages tile 15 (last staged)
    TILE(2 * BUFB, 0,        14, 0, 1, 0);   // drain: certify tile 15
    TILE(0 * BUFB, 0,        15, 0, 0, 0);   // compute only

    // ---------------- epilogue (fused, in-register) ----------------
    const int j = bcol + wj * 16 + fr;
    const float bi_ = bias[j];
    const float bf_ = bias[512 + j];
    const float bc_ = bias[1024 + j];
    const float bo_ = bias[1536 + j];
    const float be_ = bias[2048 + j];
    const long mbase = brow + wm * 64 + (q << 2);
#pragma unroll
    for (int m = 0; m < 4; ++m) {
#pragma unroll
        for (int r = 0; r < 4; ++r) {
            long row = mbase + m * 16 + r;
            float gi = acc[0][m][r] + bi_;
            float gf = acc[1][m][r] + bf_;
            float gc = acc[2][m][r] + bc_;
            float go = acc[3][m][r] + bo_;
            float ge = acc[4][m][r] + be_;
            float iv = fast_sigmoid(gi);
            float fv = fast_sigmoid(gf);
            float gv = fast_tanh(gc);
            float ov = fast_sigmoid(go);
            float ef = __expf(fast_tanh(ge));
            float cp = c_prev[row * 512 + j];
            float cv = fv * cp + iv * gv;
            float hv = ov * fast_tanh(cv) * ef;
            out[row * 512 + j] = hv;
            out[(long)Bsz * 512 + row * 512 + j] = cv;
        }
    }
}

extern "C" void kernel_launch(void* const* d_in, const int* in_sizes, int n_in,
                              void* d_out, int out_size, void* d_ws, size_t ws_size,
                              hipStream_t stream) {
    const float* x      = (const float*)d_in[0];
    const float* h_prev = (const float*)d_in[1];
    const float* c_prev = (const float*)d_in[2];
    const float* Wxi = (const float*)d_in[3];
    const float* bxi = (const float*)d_in[4];
    const float* Whi = (const float*)d_in[5];
    const float* bhi = (const float*)d_in[6];
    const float* Wxf = (const float*)d_in[7];
    const float* bxf = (const float*)d_in[8];
    const float* Whf = (const float*)d_in[9];
    const float* bhf = (const float*)d_in[10];
    const float* Wxc = (const float*)d_in[11];
    const float* bxc = (const float*)d_in[12];
    const float* Whc = (const float*)d_in[13];
    const float* bhc = (const float*)d_in[14];
    const float* Wxo = (const float*)d_in[15];
    const float* bxo = (const float*)d_in[16];
    const float* Who = (const float*)d_in[17];
    const float* bho = (const float*)d_in[18];
    const float* We  = (const float*)d_in[19];
    const float* be  = (const float*)d_in[20];

    unsigned short* Abf  = (unsigned short*)d_ws;                        // 33,554,432 B
    unsigned short* Bp   = (unsigned short*)((char*)d_ws + 33554432);    //  5,242,880 B
    float*          bias = (float*)((char*)d_ws + 33554432 + 5242880);   //     10,240 B

    pack_A<<<2048, 256, 0, stream>>>(x, h_prev, Abf);
    pack_B<<<1280, 256, 0, stream>>>(Wxi, Whi, Wxf, Whf, Wxc, Whc, Wxo, Who, We,
                                     bxi, bhi, bxf, bhf, bxc, bhc, bxo, bho, be,
                                     Bp, bias);
    xlstm_gemm<<<1024, 512, 0, stream>>>(Abf, Bp, bias, c_prev, (float*)d_out);
}